// Round 7
// baseline (36113.626 us; speedup 1.0000x reference)
//
#include <hip/hip_runtime.h>

// TimeLSTM on MI355X (gfx950). B=64,S=1024,D=128,H=256.
// ROUND-12: rounds 5-11 falsified the register-residency theory (allocator
// caps live opaque state at ~64 VGPRs regardless of pin mechanism). The
// binding constraint all along: 640KB of weights/step/block > 160KB LDS ->
// ~500KB/step streamed at the ~55 B/cyc per-CU L2 port = the measured 10k
// cyc/step. FIX: make weights LDS-RESIDENT by N-splitting the step GEMV
// across 4 cooperating blocks per sequence-pair. Block (q,p) owns gate rows
// [256p,256p+256) (128KB LDS) + W_d rows [64p,64p+64) (28KB LDS + 4KB L2
// tail). Per step: each block computes its pre-act slice + c_short slice,
// publishes 2.5KB f32 to workspace (system-scope stores), release-flag;
// peers acquire-spin (one sync/step), then ALL blocks redundantly compute
// the identical combine (published f32 -> bit-identical h,c per block).
// 2 seqs/block amortize LDS reads; 128 blocks <= 256 CUs => co-residency
// robust (no deadlock); flags re-zeroed by pack each launch (graph replay
// safe); protocol self-throttles (block can't overwrite slot s+1 before
// all peers consumed s). XCD affinity: peers {q,q+32,q+64,q+96} share
// bid%8 under round-robin (perf-only assumption; system-scope atomics
// keep it correct cross-XCD regardless).

#define B_ 64
#define S_ 1024
#define D_ 128
#define H_ 256
#define FH_ 1024

// LDS: wg 8192 chunks (131072B) + wd 1792 chunks (28672B) + h16 1KB + c16 1KB
#define WG_CH   8192
#define WD_CH   1792
#define SMEM_BYTES (131072 + 28672 + 1024 + 1024)   // 161792 <= 163840

typedef _Float16 half2_t __attribute__((ext_vector_type(2)));
typedef _Float16 half8_t __attribute__((ext_vector_type(8)));
typedef float    f32x4   __attribute__((ext_vector_type(4)));

union HW { half8_t v; half2_t p[4]; };

__device__ inline float dot2acc(half2_t a, half2_t b, float c) {
#if __has_builtin(__builtin_amdgcn_fdot2)
    return __builtin_amdgcn_fdot2(a, b, c, false);
#else
    return c + (float)a[0] * (float)b[0] + (float)a[1] * (float)b[1];
#endif
}

__device__ inline float dot8acc(half8_t a, half8_t b, float c) {
    HW ua; ua.v = a;
    HW ub; ub.v = b;
    c = dot2acc(ua.p[0], ub.p[0], c);
    c = dot2acc(ua.p[1], ub.p[1], c);
    c = dot2acc(ua.p[2], ub.p[2], c);
    c = dot2acc(ua.p[3], ub.p[3], c);
    return c;
}

__device__ inline float sigmoid_f(float x) { return 1.f / (1.f + __expf(-x)); }
__device__ inline float tanh_f(float x)    { return 1.f - 2.f / (__expf(2.f * x) + 1.f); }

__device__ inline float sysld(const float* p) {
    return __hip_atomic_load(p, __ATOMIC_RELAXED, __HIP_MEMORY_SCOPE_SYSTEM);
}
__device__ inline void sysst(float* p, float v) {
    __hip_atomic_store(p, v, __ATOMIC_RELAXED, __HIP_MEMORY_SCOPE_SYSTEM);
}

// ---------------------------------------------------------------------------
// Pack: f16 copies of W_all / W_d / U_all (plain row-major), decay, flag-zero.
// idx ranges: [0,262144) W16 | [262144,327680) Wd16 | [327680,458752) U16 |
//             [458752,524288) decay | [524288,524416) flags=0
// ---------------------------------------------------------------------------
__global__ __launch_bounds__(256) void pack_kernel(
    const float* __restrict__ Wall, const float* __restrict__ Wd,
    const float* __restrict__ Uall, const float* __restrict__ ts,
    _Float16* __restrict__ W16, _Float16* __restrict__ Wd16,
    _Float16* __restrict__ U16, float* __restrict__ decay,
    unsigned* __restrict__ flags)
{
    int idx = blockIdx.x * 256 + threadIdx.x;
    if (idx < 262144) {
        W16[idx] = (_Float16)Wall[idx];
    } else if (idx < 327680) {
        int i = idx - 262144;
        Wd16[i] = (_Float16)Wd[i];
    } else if (idx < 458752) {
        int i = idx - 327680;
        U16[i] = (_Float16)Uall[i];
    } else if (idx < 524288) {
        int i = idx - 458752;
        int bb = i >> 10, s = i & 1023;
        float d = 1.f;
        if (s > 0) {
            float dt = ts[bb * S_ + s] - ts[bb * S_ + s - 1];
            dt = fmaxf(dt, 1e-6f);
            d = 1.f / logf(2.718281828459045f + dt);
        }
        decay[i] = d;
    } else if (idx < 524416) {
        flags[idx - 524288] = 0u;
    }
}

// ---------------------------------------------------------------------------
// u GEMM via MFMA 16x16x32 f16 (unchanged, validated). u16[row][col], col =
// gate-row index (f:0..255, i:256..511, o:512..767, c~:768..1023).
// ---------------------------------------------------------------------------
__global__ __launch_bounds__(256) void u_gemm_mfma(
    const float* __restrict__ x, const _Float16* __restrict__ U16,
    const float* __restrict__ Ub, _Float16* __restrict__ u16)
{
    int wave = threadIdx.x >> 6, lane = threadIdx.x & 63;
    size_t row0 = (size_t)blockIdx.x * 64 + wave * 16;
    int n0 = blockIdx.y * 256;
    int am = lane & 15;
    int ak = (lane >> 4) * 8;
    const float* xr = x + (row0 + am) * D_ + ak;

    f32x4 acc[16];
    #pragma unroll
    for (int nt = 0; nt < 16; nt++) acc[nt] = (f32x4){0.f, 0.f, 0.f, 0.f};

    #pragma unroll
    for (int kc = 0; kc < 4; kc++) {
        half8_t a;
        #pragma unroll
        for (int e = 0; e < 8; e++) a[e] = (_Float16)xr[kc * 32 + e];
        #pragma unroll
        for (int nt = 0; nt < 16; nt++) {
            half8_t bfr = *(const half8_t*)(U16 + (size_t)(n0 + nt * 16 + am) * D_ + kc * 32 + ak);
            acc[nt] = __builtin_amdgcn_mfma_f32_16x16x32_f16(a, bfr, acc[nt], 0, 0, 0);
        }
    }

    int cr = (lane >> 4) * 4;
    #pragma unroll
    for (int nt = 0; nt < 16; nt++) {
        int col = n0 + nt * 16 + am;
        float bias = Ub[col];
        #pragma unroll
        for (int i = 0; i < 4; i++) {
            u16[(row0 + cr + i) * (size_t)FH_ + col] = (_Float16)(acc[nt][i] + bias);
        }
    }
}

// ---------------------------------------------------------------------------
// Scan. 128 blocks x 1024 threads. Block bid: p = bid>>5 (gate part 0..3),
// q = bid&31 (sequence pair: seqs 2q, 2q+1).
// ---------------------------------------------------------------------------
__global__ void __launch_bounds__(1024)
scan_kernel(
    const _Float16* __restrict__ u16, const _Float16* __restrict__ W16,
    const _Float16* __restrict__ Wd16, const float* __restrict__ Wb,
    const float* __restrict__ Wdb, const float* __restrict__ dec,
    float* __restrict__ pub_pre, float* __restrict__ pub_csh,
    unsigned* __restrict__ flags, float* __restrict__ out)
{
    int bid = blockIdx.x, t = threadIdx.x;
    int p = bid >> 5, q = bid & 31;

    extern __shared__ __align__(16) char smem[];
    half8_t*  wg  = (half8_t*)smem;                        // [32 kc][256 r]
    half8_t*  wdl = (half8_t*)(smem + 131072);             // [28 kc2][64 rd]
    _Float16* h16 = (_Float16*)(smem + 131072 + 28672);    // [2][256]
    _Float16* c16 = (_Float16*)(smem + 131072 + 28672 + 1024);

    const half8_t* __restrict__ W16_8  = (const half8_t*)W16;   // [1024][32]
    const half8_t* __restrict__ Wd16_8 = (const half8_t*)Wd16;  // [256][32]

    // ---- stage weight slices into LDS (one-time) ----
    #pragma unroll
    for (int i = 0; i < 8; i++) {
        int cid = i * 1024 + t;                 // 8192 gate chunks
        int kc = cid & 31, r = cid >> 5;
        wg[kc * 256 + (r ^ (((kc >> 3) & 1) << 2))] =
            W16_8[(size_t)(256 * p + r) * 32 + kc];
    }
    #pragma unroll
    for (int i = 0; i < 2; i++) {
        int cid = i * 1024 + t;
        int kc2 = cid >> 6, rd2 = cid & 63;
        if (kc2 < 28)
            wdl[kc2 * 64 + (rd2 ^ ((((kc2 >> 1) << 2)) & 63))] =
                Wd16_8[(size_t)(64 * p + rd2) * 32 + kc2];
    }
    if (t < 512) { h16[t] = (_Float16)0.f; c16[t] = (_Float16)0.f; }

    float bWb = Wb[256 * p + (t >> 2)];
    float bWd = Wdb[64 * p + (t >> 4)];
    float c_reg = 0.f, hn = 0.f;
    __syncthreads();

    int r  = t >> 2, kq  = t & 3;
    int rd = t >> 4, kq2 = t & 15;
    unsigned* myflag = &flags[q * 4 + p];

    for (int s = 0; s < S_; s++) {
        // ---- gate dots (both seqs share the weight read) ----
        float a0 = 0.f, a1 = 0.f;
        #pragma unroll
        for (int j = 0; j < 8; j++) {
            int kc = kq * 8 + j;
            half8_t w   = wg[kc * 256 + (r ^ (((kc >> 3) & 1) << 2))];
            half8_t hc0 = *(const half8_t*)(h16 + kq * 64 + j * 8);
            half8_t hc1 = *(const half8_t*)(h16 + 256 + kq * 64 + j * 8);
            a0 = dot8acc(hc0, w, a0);
            a1 = dot8acc(hc1, w, a1);
        }
        a0 += __shfl_xor(a0, 1); a0 += __shfl_xor(a0, 2);
        a1 += __shfl_xor(a1, 1); a1 += __shfl_xor(a1, 2);

        // ---- W_d dots ----
        float d0 = 0.f, d1 = 0.f;
        #pragma unroll
        for (int j2 = 0; j2 < 2; j2++) {
            int kc2 = kq2 * 2 + j2;
            half8_t w = (kq2 < 14)
                ? wdl[kc2 * 64 + (rd ^ ((((kc2 >> 1) << 2)) & 63))]
                : Wd16_8[(size_t)(64 * p + rd) * 32 + kc2];
            half8_t cc0 = *(const half8_t*)(c16 + kq2 * 16 + j2 * 8);
            half8_t cc1 = *(const half8_t*)(c16 + 256 + kq2 * 16 + j2 * 8);
            d0 = dot8acc(cc0, w, d0);
            d1 = dot8acc(cc1, w, d1);
        }
        d0 += __shfl_xor(d0, 1); d0 += __shfl_xor(d0, 2);
        d0 += __shfl_xor(d0, 4); d0 += __shfl_xor(d0, 8);
        d1 += __shfl_xor(d1, 1); d1 += __shfl_xor(d1, 2);
        d1 += __shfl_xor(d1, 4); d1 += __shfl_xor(d1, 8);

        // ---- publish slice (system-scope stores -> coherence point) ----
        if ((t & 3) == 0) {
            size_t u0 = ((size_t)(q * 2) * S_ + s) * FH_ + 256 * p + r;
            size_t u1 = ((size_t)(q * 2 + 1) * S_ + s) * FH_ + 256 * p + r;
            sysst(&pub_pre[((q * 4 + p) * 2 + 0) * 256 + r], a0 + bWb + (float)u16[u0]);
            sysst(&pub_pre[((q * 4 + p) * 2 + 1) * 256 + r], a1 + bWb + (float)u16[u1]);
        }
        if ((t & 15) == 0) {
            sysst(&pub_csh[((q * 4 + p) * 2 + 0) * 64 + rd], tanh_f(d0 + bWd));
            sysst(&pub_csh[((q * 4 + p) * 2 + 1) * 64 + rd], tanh_f(d1 + bWd));
        }
        __threadfence();
        __syncthreads();
        if (t == 0) {
            __hip_atomic_store(myflag, (unsigned)(s + 1), __ATOMIC_RELEASE,
                               __HIP_MEMORY_SCOPE_SYSTEM);
            #pragma unroll
            for (int pp = 0; pp < 4; pp++) {
                if (pp == p) continue;
                while (__hip_atomic_load(&flags[q * 4 + pp], __ATOMIC_ACQUIRE,
                                         __HIP_MEMORY_SCOPE_SYSTEM) < (unsigned)(s + 1)) {
                    __builtin_amdgcn_s_sleep(1);
                }
            }
        }
        __syncthreads();

        // ---- redundant combine (identical inputs -> identical h,c) ----
        if (t < 512) {
            int x = t >> 8, e = t & 255;
            float f_ = sysld(&pub_pre[((q * 4 + 0) * 2 + x) * 256 + e]);
            float i_ = sysld(&pub_pre[((q * 4 + 1) * 2 + x) * 256 + e]);
            float o_ = sysld(&pub_pre[((q * 4 + 2) * 2 + x) * 256 + e]);
            float ct = sysld(&pub_pre[((q * 4 + 3) * 2 + x) * 256 + e]);
            float cs = sysld(&pub_csh[((q * 4 + (e >> 6)) * 2 + x) * 64 + (e & 63)]);
            float dly = dec[(size_t)(q * 2 + x) * S_ + s];
            float cadj = (c_reg - cs) + cs * dly;
            float cn = sigmoid_f(f_) * cadj + sigmoid_f(i_) * tanh_f(ct);
            float hnv = sigmoid_f(o_) * tanh_f(cn);
            c_reg = cn; hn = hnv;
            h16[x * 256 + e] = (_Float16)hnv;
            c16[x * 256 + e] = (_Float16)cn;
            if (p == 0)
                out[((size_t)(q * 2 + x) * S_ + s) * H_ + e] = hnv;
        }
        __syncthreads();
    }

    if (p == 0 && t < 512) {
        int x = t >> 8, e = t & 255;
        out[(size_t)B_ * S_ * H_ + (size_t)(q * 2 + x) * H_ + e] = hn;
        out[(size_t)B_ * S_ * H_ + (size_t)B_ * H_ + (size_t)(q * 2 + x) * H_ + e] = c_reg;
    }
}

// ---------------------------------------------------------------------------
extern "C" void kernel_launch(void* const* d_in, const int* in_sizes, int n_in,
                              void* d_out, int out_size, void* d_ws, size_t ws_size,
                              hipStream_t stream) {
    const float* inputs     = (const float*)d_in[0];   // [B,S,D]
    const float* timestamps = (const float*)d_in[1];   // [B,S]
    const float* W_all_w    = (const float*)d_in[2];   // [4H,H]
    const float* W_all_b    = (const float*)d_in[3];   // [4H]
    const float* U_all_w    = (const float*)d_in[4];   // [4H,D]
    const float* U_all_b    = (const float*)d_in[5];   // [4H]
    const float* W_d_w      = (const float*)d_in[6];   // [H,H]
    const float* W_d_b      = (const float*)d_in[7];   // [H]
    float* out = (float*)d_out;

    char* p = (char*)d_ws;
    _Float16* u16  = (_Float16*)p;  p += (size_t)B_ * S_ * FH_ * 2;   // 128 MiB
    _Float16* W16  = (_Float16*)p;  p += (size_t)1024 * 256 * 2;      // 512 KiB
    _Float16* Wd16 = (_Float16*)p;  p += (size_t)256 * 256 * 2;       // 128 KiB
    _Float16* U16  = (_Float16*)p;  p += (size_t)FH_ * D_ * 2;        // 256 KiB
    float*    dec  = (float*)p;     p += (size_t)B_ * S_ * 4;         // 256 KiB
    float*    pub_pre = (float*)p;  p += (size_t)32 * 4 * 2 * 256 * 4; // 256 KiB
    float*    pub_csh = (float*)p;  p += (size_t)32 * 4 * 2 * 64 * 4;  // 64 KiB
    unsigned* flags   = (unsigned*)p;                                  // 512 B

    (void)hipFuncSetAttribute((const void*)scan_kernel,
                              hipFuncAttributeMaxDynamicSharedMemorySize,
                              SMEM_BYTES);

    pack_kernel<<<dim3(2049), dim3(256), 0, stream>>>(
        W_all_w, W_d_w, U_all_w, timestamps, W16, Wd16, U16, dec, flags);
    u_gemm_mfma<<<dim3(1024, 4), dim3(256), 0, stream>>>(
        inputs, U16, U_all_b, u16);
    scan_kernel<<<dim3(128), dim3(1024), SMEM_BYTES, stream>>>(
        u16, W16, Wd16, W_all_b, W_d_b, dec, pub_pre, pub_csh, flags, out);
}

// Round 8
// 5621.628 us; speedup vs baseline: 6.4241x; 6.4241x over previous
//
#include <hip/hip_runtime.h>

// TimeLSTM on MI355X (gfx950). B=64,S=1024,D=128,H=256.
// ROUND-13: round-12's 4-block split was structurally right but used
// SYSTEM-scope atomics (every pub byte + every flag poll went to HBM:
// WRITE_SIZE 463MB, ~35us/step spin) and exchanged 10KB/step (redundant
// pre-act combine) with a broken LDS swizzle (2.5e8 bank conflicts).
// FIX (transport, not structure):
//  * AGENT-scope atomics (resolve at IC, ~0.5us, not HBM ~0.9us+).
//  * Partition by e-slice: block p owns e in [64p,64p+64) for ALL gates
//    (256 W rows = 128KB LDS + 48 W_d rows LDS + 16 streamed). Each block
//    combines its slice LOCALLY; exchange = 64 x (h,c) f16 = 512B/step.
//  * Parity double-buffered pub (fixes round-12's latent overwrite race:
//    flag s+1 proves peers GATHERED s, so parity slot s+2 is safe).
//  * Correct XOR swizzle (c ^ row&31) on wg/wd -> conflict-free-ish reads.
//  * Combine+publish+flag+spin all in wave 0 (wave-wide vmcnt orders pub
//    stores before the release), 3 barriers/step.
// Groups {q, q+32, q+64, q+96} share bid%8 -> same XCD (perf-only).
// 128 blocks x 256 thr, 2 seqs/block; co-residency proven in round 12.

#define B_ 64
#define S_ 1024
#define D_ 128
#define H_ 256
#define FH_ 1024

// LDS: wg 131072 | wd 24576 | h16 1024 | c16 1024 | pg 2048 | pd 512
#define SMEM_BYTES 160256

typedef _Float16 half2_t __attribute__((ext_vector_type(2)));
typedef _Float16 half8_t __attribute__((ext_vector_type(8)));
typedef float    f32x4   __attribute__((ext_vector_type(4)));

union HW  { half8_t v; half2_t p[4]; };
union HCP { unsigned u; _Float16 hc[2]; };

__device__ inline float dot2acc(half2_t a, half2_t b, float c) {
#if __has_builtin(__builtin_amdgcn_fdot2)
    return __builtin_amdgcn_fdot2(a, b, c, false);
#else
    return c + (float)a[0] * (float)b[0] + (float)a[1] * (float)b[1];
#endif
}

__device__ inline float dot8acc(half8_t a, half8_t b, float c) {
    HW ua; ua.v = a;
    HW ub; ub.v = b;
    c = dot2acc(ua.p[0], ub.p[0], c);
    c = dot2acc(ua.p[1], ub.p[1], c);
    c = dot2acc(ua.p[2], ub.p[2], c);
    c = dot2acc(ua.p[3], ub.p[3], c);
    return c;
}

__device__ inline float sigmoid_f(float x) { return 1.f / (1.f + __expf(-x)); }
__device__ inline float tanh_f(float x)    { return 1.f - 2.f / (__expf(2.f * x) + 1.f); }

__device__ inline unsigned ag_load(const unsigned* p) {
    return __hip_atomic_load(p, __ATOMIC_RELAXED, __HIP_MEMORY_SCOPE_AGENT);
}
__device__ inline void ag_store(unsigned* p, unsigned v) {
    __hip_atomic_store(p, v, __ATOMIC_RELAXED, __HIP_MEMORY_SCOPE_AGENT);
}

// ---------------------------------------------------------------------------
// Pack: f16 copies (plain row-major) + decay + flag zeroing.
// idx: [0,262144) W16 | [262144,327680) Wd16 | [327680,458752) U16 |
//      [458752,524288) decay | [524288,524416) flags=0
// ---------------------------------------------------------------------------
__global__ __launch_bounds__(256) void pack_kernel(
    const float* __restrict__ Wall, const float* __restrict__ Wd,
    const float* __restrict__ Uall, const float* __restrict__ ts,
    _Float16* __restrict__ W16, _Float16* __restrict__ Wd16,
    _Float16* __restrict__ U16, float* __restrict__ decay,
    unsigned* __restrict__ flags)
{
    int idx = blockIdx.x * 256 + threadIdx.x;
    if (idx < 262144) {
        W16[idx] = (_Float16)Wall[idx];
    } else if (idx < 327680) {
        int i = idx - 262144;
        Wd16[i] = (_Float16)Wd[i];
    } else if (idx < 458752) {
        int i = idx - 327680;
        U16[i] = (_Float16)Uall[i];
    } else if (idx < 524288) {
        int i = idx - 458752;
        int bb = i >> 10, s = i & 1023;
        float d = 1.f;
        if (s > 0) {
            float dt = ts[bb * S_ + s] - ts[bb * S_ + s - 1];
            dt = fmaxf(dt, 1e-6f);
            d = 1.f / logf(2.718281828459045f + dt);
        }
        decay[i] = d;
    } else if (idx < 524416) {
        flags[idx - 524288] = 0u;
    }
}

// ---------------------------------------------------------------------------
// u GEMM via MFMA 16x16x32 f16 (validated rounds 10-11). u16[row][col],
// col = gate-row index (f:0..255, i:256..511, o:512..767, c~:768..1023).
// ---------------------------------------------------------------------------
__global__ __launch_bounds__(256) void u_gemm_mfma(
    const float* __restrict__ x, const _Float16* __restrict__ U16,
    const float* __restrict__ Ub, _Float16* __restrict__ u16)
{
    int wave = threadIdx.x >> 6, lane = threadIdx.x & 63;
    size_t row0 = (size_t)blockIdx.x * 64 + wave * 16;
    int n0 = blockIdx.y * 256;
    int am = lane & 15;
    int ak = (lane >> 4) * 8;
    const float* xr = x + (row0 + am) * D_ + ak;

    f32x4 acc[16];
    #pragma unroll
    for (int nt = 0; nt < 16; nt++) acc[nt] = (f32x4){0.f, 0.f, 0.f, 0.f};

    #pragma unroll
    for (int kc = 0; kc < 4; kc++) {
        half8_t a;
        #pragma unroll
        for (int e = 0; e < 8; e++) a[e] = (_Float16)xr[kc * 32 + e];
        #pragma unroll
        for (int nt = 0; nt < 16; nt++) {
            half8_t bfr = *(const half8_t*)(U16 + (size_t)(n0 + nt * 16 + am) * D_ + kc * 32 + ak);
            acc[nt] = __builtin_amdgcn_mfma_f32_16x16x32_f16(a, bfr, acc[nt], 0, 0, 0);
        }
    }

    int cr = (lane >> 4) * 4;
    #pragma unroll
    for (int nt = 0; nt < 16; nt++) {
        int col = n0 + nt * 16 + am;
        float bias = Ub[col];
        #pragma unroll
        for (int i = 0; i < 4; i++) {
            u16[(row0 + cr + i) * (size_t)FH_ + col] = (_Float16)(acc[nt][i] + bias);
        }
    }
}

// ---------------------------------------------------------------------------
// Scan. 128 blocks x 256 threads. p = bid>>5 (e-slice part), q = bid&31
// (seq pair 2q, 2q+1). Thread t: gate g=t>>6, e_loc=t&63 -> W row
// g*256 + 64p + e_loc.
// ---------------------------------------------------------------------------
__global__ void __launch_bounds__(256)
scan_kernel(
    const _Float16* __restrict__ u16, const _Float16* __restrict__ W16,
    const _Float16* __restrict__ Wd16, const float* __restrict__ Wb,
    const float* __restrict__ Wdb, const float* __restrict__ dec,
    unsigned* __restrict__ pub, unsigned* __restrict__ flags,
    float* __restrict__ out)
{
    int bid = blockIdx.x, t = threadIdx.x;
    int p = bid >> 5, q = bid & 31;
    int g = t >> 6, el = t & 63;
    int wrow = g * 256 + 64 * p + el;

    extern __shared__ __align__(16) char smem[];
    half8_t*  wg  = (half8_t*)smem;                     // [256 rows][32 ch]
    half8_t*  wd  = (half8_t*)(smem + 131072);          // [48 rows][32 ch]
    _Float16* h16 = (_Float16*)(smem + 155648);         // [2][256]
    _Float16* c16 = (_Float16*)(smem + 156672);         // [2][256]
    float*    pg  = (float*)(smem + 157696);            // [2][256]
    float*    pd  = (float*)(smem + 159744);            // [2][64]

    const half8_t* __restrict__ W16_8  = (const half8_t*)W16;   // [1024][32]
    const half8_t* __restrict__ Wd16_8 = (const half8_t*)Wd16;  // [256][32]

    // ---- one-time staging ----
    #pragma unroll
    for (int i = 0; i < 32; i++) {
        int cid = i * 256 + t;
        int rl = cid >> 5, c = cid & 31;
        int gg = rl >> 6, ee = rl & 63;
        wg[rl * 32 + (c ^ (rl & 31))] =
            W16_8[(size_t)(gg * 256 + 64 * p + ee) * 32 + c];
    }
    #pragma unroll
    for (int i = 0; i < 6; i++) {
        int cid = i * 256 + t;
        int e = cid >> 5, c = cid & 31;
        wd[e * 32 + (c ^ (e & 31))] = Wd16_8[(size_t)(64 * p + e) * 32 + c];
    }
    h16[t] = (_Float16)0.f; h16[256 + t] = (_Float16)0.f;
    c16[t] = (_Float16)0.f; c16[256 + t] = (_Float16)0.f;

    float bWb = Wb[wrow];
    float bWd = (t < 64) ? Wdb[64 * p + t] : 0.f;
    float c_reg0 = 0.f, c_reg1 = 0.f, hn0 = 0.f, hn1 = 0.f;
    __syncthreads();

    const _Float16* __restrict__ ub0 = u16 + ((size_t)(2 * q)     * S_) * FH_ + wrow;
    const _Float16* __restrict__ ub1 = u16 + ((size_t)(2 * q + 1) * S_) * FH_ + wrow;
    int e2 = t >> 2, kq = t & 3, sw = t & 31, sw2 = e2 & 31;
    unsigned* myflag = &flags[q * 4 + p];
    const size_t pubbase = (size_t)(q * 4) * 256;   // group base (4p x 2x x 2par x 64)

    for (int s = 0; s < S_; s++) {
        // ---- gate-row dots (both seqs share the LDS weight read) ----
        const half8_t* hb0 = (const half8_t*)h16;
        const half8_t* hb1 = (const half8_t*)(h16 + 256);
        float a0 = 0.f, a1 = 0.f;
        #pragma unroll
        for (int c = 0; c < 32; c++) {
            half8_t w = wg[t * 32 + (c ^ sw)];
            a0 = dot8acc(hb0[c], w, a0);
            a1 = dot8acc(hb1[c], w, a1);
        }
        pg[t]       = a0 + bWb + (float)ub0[(size_t)s * FH_];
        pg[256 + t] = a1 + bWb + (float)ub1[(size_t)s * FH_];

        // ---- W_d dots: row e2, k-quarter kq (waves 0-2 LDS, wave 3 L2) ----
        const half8_t* cb0 = (const half8_t*)c16;
        const half8_t* cb1 = (const half8_t*)(c16 + 256);
        float d0 = 0.f, d1 = 0.f;
        if (e2 < 48) {
            #pragma unroll
            for (int j = 0; j < 8; j++) {
                int c = kq * 8 + j;
                half8_t w = wd[e2 * 32 + (c ^ sw2)];
                d0 = dot8acc(cb0[c], w, d0);
                d1 = dot8acc(cb1[c], w, d1);
            }
        } else {
            const half8_t* wr = Wd16_8 + (size_t)(64 * p + e2) * 32;
            #pragma unroll
            for (int j = 0; j < 8; j++) {
                int c = kq * 8 + j;
                half8_t w = wr[c];
                d0 = dot8acc(cb0[c], w, d0);
                d1 = dot8acc(cb1[c], w, d1);
            }
        }
        d0 += __shfl_xor(d0, 1); d0 += __shfl_xor(d0, 2);
        d1 += __shfl_xor(d1, 1); d1 += __shfl_xor(d1, 2);
        if (kq == 0) { pd[e2] = d0; pd[64 + e2] = d1; }
        __syncthreads();                                   // B1

        // ---- local combine + publish (wave 0 only) ----
        if (t < 64) {
            int par = s & 1;
            float dly0 = dec[(size_t)(2 * q) * S_ + s];
            float dly1 = dec[(size_t)(2 * q + 1) * S_ + s];
            // seq 0
            {
                float f_ = pg[t], i_ = pg[64 + t], o_ = pg[128 + t], ct = pg[192 + t];
                float cs = tanh_f(pd[t] + bWd);
                float cadj = (c_reg0 - cs) + cs * dly0;
                float cn = sigmoid_f(f_) * cadj + sigmoid_f(i_) * tanh_f(ct);
                hn0 = sigmoid_f(o_) * tanh_f(cn);
                c_reg0 = cn;
                out[((size_t)(2 * q) * S_ + s) * H_ + 64 * p + t] = hn0;
                h16[64 * p + t] = (_Float16)hn0;
                c16[64 * p + t] = (_Float16)cn;
                HCP pk; pk.hc[0] = (_Float16)hn0; pk.hc[1] = (_Float16)cn;
                ag_store(&pub[pubbase + ((p * 2 + 0) * 2 + par) * 64 + t], pk.u);
            }
            // seq 1
            {
                float f_ = pg[256 + t], i_ = pg[320 + t], o_ = pg[384 + t], ct = pg[448 + t];
                float cs = tanh_f(pd[64 + t] + bWd);
                float cadj = (c_reg1 - cs) + cs * dly1;
                float cn = sigmoid_f(f_) * cadj + sigmoid_f(i_) * tanh_f(ct);
                hn1 = sigmoid_f(o_) * tanh_f(cn);
                c_reg1 = cn;
                out[((size_t)(2 * q + 1) * S_ + s) * H_ + 64 * p + t] = hn1;
                h16[256 + 64 * p + t] = (_Float16)hn1;
                c16[256 + 64 * p + t] = (_Float16)cn;
                HCP pk; pk.hc[0] = (_Float16)hn1; pk.hc[1] = (_Float16)cn;
                ag_store(&pub[pubbase + ((p * 2 + 1) * 2 + par) * 64 + t], pk.u);
            }
        }
        // release (wave 0; wave-wide vmcnt orders the pub stores first)
        if (t == 0)
            __hip_atomic_store(myflag, (unsigned)(s + 1), __ATOMIC_RELEASE,
                               __HIP_MEMORY_SCOPE_AGENT);
        // spin: lanes 0..2 poll the 3 peers in parallel
        if (t < 3) {
            int pp = t + (t >= p);
            while (__hip_atomic_load(&flags[q * 4 + pp], __ATOMIC_ACQUIRE,
                                     __HIP_MEMORY_SCOPE_AGENT) < (unsigned)(s + 1)) {
                __builtin_amdgcn_s_sleep(1);
            }
        }
        __syncthreads();                                   // B2

        // ---- gather peer h/c slices ----
        if (t < 192) {
            int pi = t >> 6;
            int pp = pi + (pi >= p);
            int e3 = t & 63;
            int par = s & 1;
            HCP k0, k1;
            k0.u = ag_load(&pub[pubbase + ((pp * 2 + 0) * 2 + par) * 64 + e3]);
            k1.u = ag_load(&pub[pubbase + ((pp * 2 + 1) * 2 + par) * 64 + e3]);
            h16[64 * pp + e3]       = k0.hc[0];
            c16[64 * pp + e3]       = k0.hc[1];
            h16[256 + 64 * pp + e3] = k1.hc[0];
            c16[256 + 64 * pp + e3] = k1.hc[1];
        }
        __syncthreads();                                   // B3
    }

    if (t < 64) {
        out[(size_t)B_ * S_ * H_ + (size_t)(2 * q) * H_ + 64 * p + t] = hn0;
        out[(size_t)B_ * S_ * H_ + (size_t)(2 * q + 1) * H_ + 64 * p + t] = hn1;
        out[(size_t)B_ * S_ * H_ + (size_t)B_ * H_ + (size_t)(2 * q) * H_ + 64 * p + t] = c_reg0;
        out[(size_t)B_ * S_ * H_ + (size_t)B_ * H_ + (size_t)(2 * q + 1) * H_ + 64 * p + t] = c_reg1;
    }
}

// ---------------------------------------------------------------------------
extern "C" void kernel_launch(void* const* d_in, const int* in_sizes, int n_in,
                              void* d_out, int out_size, void* d_ws, size_t ws_size,
                              hipStream_t stream) {
    const float* inputs     = (const float*)d_in[0];   // [B,S,D]
    const float* timestamps = (const float*)d_in[1];   // [B,S]
    const float* W_all_w    = (const float*)d_in[2];   // [4H,H]
    const float* W_all_b    = (const float*)d_in[3];   // [4H]
    const float* U_all_w    = (const float*)d_in[4];   // [4H,D]
    const float* U_all_b    = (const float*)d_in[5];   // [4H]
    const float* W_d_w      = (const float*)d_in[6];   // [H,H]
    const float* W_d_b      = (const float*)d_in[7];   // [H]
    float* out = (float*)d_out;

    char* p = (char*)d_ws;
    _Float16* u16  = (_Float16*)p;  p += (size_t)B_ * S_ * FH_ * 2;   // 128 MiB
    _Float16* W16  = (_Float16*)p;  p += (size_t)1024 * 256 * 2;      // 512 KiB
    _Float16* Wd16 = (_Float16*)p;  p += (size_t)256 * 256 * 2;       // 128 KiB
    _Float16* U16  = (_Float16*)p;  p += (size_t)FH_ * D_ * 2;        // 256 KiB
    float*    dec  = (float*)p;     p += (size_t)B_ * S_ * 4;         // 256 KiB
    unsigned* pub  = (unsigned*)p;  p += (size_t)32 * 4 * 2 * 2 * 64 * 4; // 128 KiB
    unsigned* flags = (unsigned*)p;                                    // 512 B

    (void)hipFuncSetAttribute((const void*)scan_kernel,
                              hipFuncAttributeMaxDynamicSharedMemorySize,
                              SMEM_BYTES);

    pack_kernel<<<dim3(2049), dim3(256), 0, stream>>>(
        W_all_w, W_d_w, U_all_w, timestamps, W16, Wd16, U16, dec, flags);
    u_gemm_mfma<<<dim3(1024, 4), dim3(256), 0, stream>>>(
        inputs, U16, U_all_b, u16);
    scan_kernel<<<dim3(128), dim3(256), SMEM_BYTES, stream>>>(
        u16, W16, Wd16, W_all_b, W_d_b, dec, pub, flags, out);
}